// Round 8
// baseline (2818.317 us; speedup 1.0000x reference)
//
#include <hip/hip_runtime.h>

#define FF 512
#define LL 12288
#define NJC 1556   // XB chunk count: max jc touched = 1549 (incl. K-roundup + prefetch)
#define NR 128     // XB rows = 16 shifts x 8 batches

typedef _Float16 half8 __attribute__((ext_vector_type(8)));
typedef float    f32x4 __attribute__((ext_vector_type(4)));

// ---------------- Fused prologue: 3 ranges of blockIdx, disjoint outputs ----
// [0,3072)        build_At : kernel fp32 -> f16, MFMA-A-fragment tiled
//                  At chunk (ft,dc,lane): elem_i = kernel[ft*16+(lane&15)][dc*32+(lane>>4)*8+i]
// [3072,3850)     build_XB : B chunk-major; XB[jc][s*8+b] elem_i = x_b[LL-1-(8jc+i)-s]
//                  (zero when idx<0 -> causal mask, incl. jc>=1536 pad tail)
// [3850,5386)     init_out : out = dense_b broadcast
__global__ __launch_bounds__(256) void prologue(const float* __restrict__ kern,
                                                _Float16* __restrict__ At,
                                                const int* __restrict__ ex,
                                                _Float16* __restrict__ XB,
                                                const float* __restrict__ db,
                                                float* __restrict__ out) {
    int bxx = blockIdx.x;
    if (bxx < 3072) {
        int tid  = bxx * 256 + threadIdx.x;             // 786432 = 512*12288/8
        int lane = tid & 63;
        int rest = tid >> 6;                            // ft*384 + dc
        int dc   = rest % 384;
        int ft   = rest / 384;
        int f    = ft * 16 + (lane & 15);
        int d0   = dc * 32 + (lane >> 4) * 8;
        const float* src = kern + (size_t)f * LL + d0;
        half8 v;
#pragma unroll
        for (int i = 0; i < 8; ++i) v[i] = (_Float16)src[i];
        ((half8*)At)[tid] = v;
    } else if (bxx < 3850) {
        int tid = (bxx - 3072) * 256 + threadIdx.x;     // 199168 = NJC*NR
        if (tid >= NJC * NR) return;
        int r  = tid & 127;
        int jc = tid >> 7;
        int s  = r >> 3, b = r & 7;
        int j0 = jc * 8;
        half8 v;
#pragma unroll
        for (int i = 0; i < 8; ++i) {
            int idx = LL - 1 - (j0 + i) - s;
            float x = 0.f;
            if (idx >= 0) x = (float)ex[b * LL + idx] * 0.5f - 1.0f;
            v[i] = (_Float16)x;
        }
        ((half8*)XB)[tid] = v;
    } else {
        int tid = (bxx - 3850) * 256 + threadIdx.x;     // 393216
        out[tid] = db[tid & 3];
    }
}

__device__ __forceinline__ void gl_lds16(const half8* g, half8* l) {
    __builtin_amdgcn_global_load_lds((const __attribute__((address_space(1))) void*)g,
                                     (__attribute__((address_space(3))) void*)l, 16, 0, 0);
}

// ---------------- Main: A via LDS (BK=96 macro-steps), B register-direct ---
// Block 128f x 256cols, 4 waves, wave tile 128x64 (8x4 mfma 16x16x32 f16).
// BK=96: 3 K32 sub-steps per macro; A tile 24KB double-buffered = 48KB LDS
// -> fits THREE blocks/CU (144 <= 160 KB), 3 waves/SIMD for latency coverage
// (launch_bounds(256,3)). Regs: 128 acc + ~104 VGPR = 232 << 682/wave cap.
// PHASE-INTERLOCK (T5, entry-only): each sub-step's 32-MFMA cluster starts at
// an s_barrier and runs at setprio(1); no exit barrier. No sched_barrier
// walls, no manual waitcnt. K rounded up to x3; tail MFMAs hit XB's causal
// zero pad (max jc = 1549 < NJC).
__global__ __launch_bounds__(256, 3) void conv_main(const _Float16* __restrict__ At,
                                                    const _Float16* __restrict__ XB,
                                                    const float* __restrict__ bias,
                                                    const float* __restrict__ dw,
                                                    float* __restrict__ out) {
    __shared__ half8 Abuf[2][3][8][64];   // 48 KB: [buf][sub][ft][lane]

    int bx    = blockIdx.x;
    int slot  = bx & 7;                // XCD pin: f_blk per XCD pair for L2 reuse
    int f_blk = slot >> 1;             // [0,4)
    int n_blk = 383 - ((bx >> 3) * 2 + (slot & 1));   // largest K first
    int n0 = n_blk << 5;
    int M  = (n_blk + 3) / 3;          // ceil((n_blk+1)/3) macro (BK=96) steps

    int tid  = threadIdx.x;
    int lane = tid & 63;
    int wid  = tid >> 6;
    int quad = lane >> 4;
    int bb   = lane & 7;
    int nh   = (lane >> 3) & 1;

    // A staging: wave wid stages ft = wid and wid+4; 1KB contiguous per load.
    const half8* Ag  = (const half8*)At;
    const half8* ag0 = Ag + ((size_t)(f_blk * 8 + wid) * 384) * 64 + lane;
    const half8* ag1 = Ag + ((size_t)(f_blk * 8 + wid + 4) * 384) * 64 + lane;

    // B pointers (half8 units): idx = jc*128 + r; per-K32 advance = 4*128 = 512.
    const half8* Bg = (const half8*)XB;
    int jc0 = 1534 - 4 * n_blk + quad - 2 * nh;
    const half8* pB[4];
#pragma unroll
    for (int t = 0; t < 4; ++t) {
        int tt = wid * 4 + t;
        int r  = (15 - tt) * 8 + bb;
        pB[t] = Bg + (size_t)jc0 * 128 + r;
    }

    f32x4 acc[8][4];
#pragma unroll
    for (int r8 = 0; r8 < 8; ++r8)
#pragma unroll
        for (int t = 0; t < 4; ++t) acc[r8][t] = (f32x4){0.f, 0.f, 0.f, 0.f};

    // prologue: stage macro 0 -> buf0, load B(0)
#pragma unroll
    for (int sub = 0; sub < 3; ++sub) {
        gl_lds16(ag0 + (size_t)sub * 64, &Abuf[0][sub][wid][lane]);
        gl_lds16(ag1 + (size_t)sub * 64, &Abuf[0][sub][wid + 4][lane]);
    }
    half8 bcur[4], bnxt[4];
#pragma unroll
    for (int t = 0; t < 4; ++t) bcur[t] = pB[t][0];
    __syncthreads();

    for (int mc = 0; mc < M; ++mc) {
        int buf = mc & 1;
        if (mc + 1 < M) {
            size_t oa = (size_t)(mc + 1) * 192;           // 3 subs x 64 chunks
#pragma unroll
            for (int sub = 0; sub < 3; ++sub) {
                gl_lds16(ag0 + oa + (size_t)sub * 64, &Abuf[buf ^ 1][sub][wid][lane]);
                gl_lds16(ag1 + oa + (size_t)sub * 64, &Abuf[buf ^ 1][sub][wid + 4][lane]);
            }
        }
#pragma unroll
        for (int sub = 0; sub < 3; ++sub) {
            int dc = mc * 3 + sub;
            size_t ob = (size_t)(dc + 1) * 512;
#pragma unroll
            for (int t = 0; t < 4; ++t) bnxt[t] = pB[t][ob];
            half8 a[8];
#pragma unroll
            for (int r8 = 0; r8 < 8; ++r8) a[r8] = Abuf[buf][sub][r8][lane];
            __builtin_amdgcn_s_barrier();          // cluster entry: waves aligned
            __builtin_amdgcn_s_setprio(1);
#pragma unroll
            for (int r8 = 0; r8 < 8; ++r8)
#pragma unroll
                for (int t = 0; t < 4; ++t)
                    acc[r8][t] = __builtin_amdgcn_mfma_f32_16x16x32_f16(a[r8], bcur[t], acc[r8][t], 0, 0, 0);
            __builtin_amdgcn_s_setprio(0);
#pragma unroll
            for (int t = 0; t < 4; ++t) bcur[t] = bnxt[t];
        }
        __syncthreads();
    }

    // Epilogue: bias + relu + dense over this block's 128 f rows.
    // C/D layout: col = lane&15, row = quad*4 + reg.
    float p[4][4] = {{0.f}};
#pragma unroll
    for (int r8 = 0; r8 < 8; ++r8) {
#pragma unroll
        for (int reg = 0; reg < 4; ++reg) {
            int f = f_blk * 128 + r8 * 16 + quad * 4 + reg;
            float bs = bias[f];
            float4 w = *(const float4*)(dw + (size_t)f * 4);
#pragma unroll
            for (int t = 0; t < 4; ++t) {
                float y = fmaxf(acc[r8][t][reg] + bs, 0.f);
                p[t][0] += y * w.x; p[t][1] += y * w.y;
                p[t][2] += y * w.z; p[t][3] += y * w.w;
            }
        }
    }
#pragma unroll
    for (int t = 0; t < 4; ++t)
#pragma unroll
        for (int c = 0; c < 4; ++c) {
            float v = p[t][c];
            v += __shfl_xor(v, 16, 64);
            v += __shfl_xor(v, 32, 64);
            p[t][c] = v;
        }
    if (quad == 0) {
#pragma unroll
        for (int t = 0; t < 4; ++t) {
            int n = n0 + (wid * 4 + t) + 16 * nh;
            float* o = out + ((size_t)bb * LL + n) * 4;
#pragma unroll
            for (int c = 0; c < 4; ++c) atomicAdd(o + c, p[t][c]);
        }
    }
}

extern "C" void kernel_launch(void* const* d_in, const int* in_sizes, int n_in,
                              void* d_out, int out_size, void* d_ws, size_t ws_size,
                              hipStream_t stream) {
    const int*   ex   = (const int*)d_in[0];
    const float* kern = (const float*)d_in[1];
    const float* bias = (const float*)d_in[2];
    const float* dw   = (const float*)d_in[3];
    const float* db   = (const float*)d_in[4];
    float* out = (float*)d_out;

    _Float16* At = (_Float16*)d_ws;                                   // 12.58 MB
    _Float16* XB = (_Float16*)((char*)d_ws + (size_t)FF * LL * 2);    // +3.05 MB

    hipLaunchKernelGGL(prologue, dim3(5386), dim3(256), 0, stream,
                       kern, At, ex, XB, db, out);
    hipLaunchKernelGGL(conv_main, dim3(1536), dim3(256), 0, stream, At, XB, bias, dw, out);
}

// Round 9
// 629.625 us; speedup vs baseline: 4.4762x; 4.4762x over previous
//
#include <hip/hip_runtime.h>

#define FF 512
#define LL 12288
#define NJC 1556   // XB chunk count: max jc touched = 1553 (incl. K-roundup + prefetch)
#define NR 128     // XB rows = 16 shifts x 8 batches

typedef _Float16 half8 __attribute__((ext_vector_type(8)));
typedef float    f32x4 __attribute__((ext_vector_type(4)));

// ---------------- Fused prologue: 3 ranges of blockIdx, disjoint outputs ----
// [0,3072)        build_At : kernel fp32 -> f16, MFMA-A-fragment tiled
//                  At chunk (ft,dc,lane): elem_i = kernel[ft*16+(lane&15)][dc*32+(lane>>4)*8+i]
// [3072,3850)     build_XB : B chunk-major; XB[jc][s*8+b] elem_i = x_b[LL-1-(8jc+i)-s]
//                  (zero when idx<0 -> causal mask, incl. jc>=1536 pad tail)
// [3850,5386)     init_out : out = dense_b broadcast
__global__ __launch_bounds__(256) void prologue(const float* __restrict__ kern,
                                                _Float16* __restrict__ At,
                                                const int* __restrict__ ex,
                                                _Float16* __restrict__ XB,
                                                const float* __restrict__ db,
                                                float* __restrict__ out) {
    int bxx = blockIdx.x;
    if (bxx < 3072) {
        int tid  = bxx * 256 + threadIdx.x;             // 786432 = 512*12288/8
        int lane = tid & 63;
        int rest = tid >> 6;                            // ft*384 + dc
        int dc   = rest % 384;
        int ft   = rest / 384;
        int f    = ft * 16 + (lane & 15);
        int d0   = dc * 32 + (lane >> 4) * 8;
        const float* src = kern + (size_t)f * LL + d0;
        half8 v;
#pragma unroll
        for (int i = 0; i < 8; ++i) v[i] = (_Float16)src[i];
        ((half8*)At)[tid] = v;
    } else if (bxx < 3850) {
        int tid = (bxx - 3072) * 256 + threadIdx.x;     // 199168 = NJC*NR
        if (tid >= NJC * NR) return;
        int r  = tid & 127;
        int jc = tid >> 7;
        int s  = r >> 3, b = r & 7;
        int j0 = jc * 8;
        half8 v;
#pragma unroll
        for (int i = 0; i < 8; ++i) {
            int idx = LL - 1 - (j0 + i) - s;
            float x = 0.f;
            if (idx >= 0) x = (float)ex[b * LL + idx] * 0.5f - 1.0f;
            v[i] = (_Float16)x;
        }
        ((half8*)XB)[tid] = v;
    } else {
        int tid = (bxx - 3850) * 256 + threadIdx.x;     // 393216
        out[tid] = db[tid & 3];
    }
}

__device__ __forceinline__ void gl_lds16(const half8* g, half8* l) {
    __builtin_amdgcn_global_load_lds((const __attribute__((address_space(1))) void*)g,
                                     (__attribute__((address_space(3))) void*)l, 16, 0, 0);
}

// ---------------- Main: 64f x 256col blocks, PAIRED n-tiles, 3 blocks/CU ---
// Each of 1536 blocks: f_blk = bx&7 (one 64-row f-slice per XCD -> A slice
// 1.57 MB L2-resident), pair p = bx>>3 in [0,192): processes n-tile 383-p then
// p (K_total = 385 K32-steps for EVERY block -> perfectly equal durations;
// 1536 = 2 exact rounds of 768 resident). 4 waves, wave tile 64f x 64col
// (4x4 mfma 16x16x32, acc = 64 VGPR -> ~145 total, fits 3 waves/SIMD at the
// 170-reg tier; r8's spill was acc=128 at this tier). LDS: BK=128 A tile
// 16KB double-buffered = 32KB -> 3 blocks/CU = 96KB. All 4 waves read all 4
// A ftiles; wave wid stages ftile wid (4 gl_lds/macro).
// PHASE-INTERLOCK kept from r7: entry s_barrier + setprio(1) per 16-MFMA
// cluster, no exit barrier. K rounded up to x4; tail MFMAs hit XB's causal
// zero pad.
__global__ __launch_bounds__(256, 3) void conv_main(const _Float16* __restrict__ At,
                                                    const _Float16* __restrict__ XB,
                                                    const float* __restrict__ bias,
                                                    const float* __restrict__ dw,
                                                    float* __restrict__ out) {
    __shared__ half8 Abuf[2][4][4][64];   // 32 KB: [buf][sub][ftile][lane]

    int bx    = blockIdx.x;
    int f_blk = bx & 7;                // one f-slice (64 rows) per XCD
    int pp    = bx >> 3;               // pair index [0,192)

    int tid  = threadIdx.x;
    int lane = tid & 63;
    int wid  = tid >> 6;
    int quad = lane >> 4;
    int bb   = lane & 7;
    int nh   = (lane >> 3) & 1;

    // A staging base: wave wid owns ftile f_blk*4 + wid.
    const half8* Ag = (const half8*)At;
    const half8* ag = Ag + ((size_t)(f_blk * 4 + wid) * 384) * 64 + lane;
    const half8* Bg = (const half8*)XB;

    for (int tile = 0; tile < 2; ++tile) {
        int n_blk = tile ? pp : 383 - pp;
        int n0 = n_blk << 5;
        int M  = (n_blk + 4) >> 2;     // ceil((n_blk+1)/4) macro (BK=128) steps

        // B pointers (half8 units): idx = jc*128 + r; per-K32 advance = 512.
        int jc0 = 1534 - 4 * n_blk + quad - 2 * nh;
        const half8* pB[4];
#pragma unroll
        for (int t = 0; t < 4; ++t) {
            int tt = wid * 4 + t;
            int r  = (15 - tt) * 8 + bb;
            pB[t] = Bg + (size_t)jc0 * 128 + r;
        }

        f32x4 acc[4][4];
#pragma unroll
        for (int rf = 0; rf < 4; ++rf)
#pragma unroll
            for (int t = 0; t < 4; ++t) acc[rf][t] = (f32x4){0.f, 0.f, 0.f, 0.f};

        // tile prologue: stage macro 0 -> buf0, load B(0)
#pragma unroll
        for (int sub = 0; sub < 4; ++sub)
            gl_lds16(ag + (size_t)sub * 64, &Abuf[0][sub][wid][lane]);
        half8 bcur[4], bnxt[4];
#pragma unroll
        for (int t = 0; t < 4; ++t) bcur[t] = pB[t][0];
        __syncthreads();               // drains vmcnt: staged A + B visible

        for (int mc = 0; mc < M; ++mc) {
            int buf = mc & 1;
            if (mc + 1 < M) {
                size_t oa = (size_t)(mc + 1) * 256;       // 4 subs x 64 chunks
#pragma unroll
                for (int sub = 0; sub < 4; ++sub)
                    gl_lds16(ag + oa + (size_t)sub * 64, &Abuf[buf ^ 1][sub][wid][lane]);
            }
#pragma unroll
            for (int sub = 0; sub < 4; ++sub) {
                int dc = mc * 4 + sub;
                size_t ob = (size_t)(dc + 1) * 512;
#pragma unroll
                for (int t = 0; t < 4; ++t) bnxt[t] = pB[t][ob];
                half8 a[4];
#pragma unroll
                for (int rf = 0; rf < 4; ++rf) a[rf] = Abuf[buf][sub][rf][lane];
                __builtin_amdgcn_s_barrier();      // cluster entry: waves aligned
                __builtin_amdgcn_s_setprio(1);
#pragma unroll
                for (int rf = 0; rf < 4; ++rf)
#pragma unroll
                    for (int t = 0; t < 4; ++t)
                        acc[rf][t] = __builtin_amdgcn_mfma_f32_16x16x32_f16(a[rf], bcur[t], acc[rf][t], 0, 0, 0);
                __builtin_amdgcn_s_setprio(0);
#pragma unroll
                for (int t = 0; t < 4; ++t) bcur[t] = bnxt[t];
            }
            __syncthreads();
        }

        // tile epilogue: bias + relu + dense over this block's 64 f rows.
        // C/D layout: col = lane&15, row = quad*4 + reg.
        float p[4][4] = {{0.f}};
#pragma unroll
        for (int rf = 0; rf < 4; ++rf) {
#pragma unroll
            for (int reg = 0; reg < 4; ++reg) {
                int f = f_blk * 64 + rf * 16 + quad * 4 + reg;
                float bs = bias[f];
                float4 w = *(const float4*)(dw + (size_t)f * 4);
#pragma unroll
                for (int t = 0; t < 4; ++t) {
                    float y = fmaxf(acc[rf][t][reg] + bs, 0.f);
                    p[t][0] += y * w.x; p[t][1] += y * w.y;
                    p[t][2] += y * w.z; p[t][3] += y * w.w;
                }
            }
        }
#pragma unroll
        for (int t = 0; t < 4; ++t)
#pragma unroll
            for (int c = 0; c < 4; ++c) {
                float v = p[t][c];
                v += __shfl_xor(v, 16, 64);
                v += __shfl_xor(v, 32, 64);
                p[t][c] = v;
            }
        if (quad == 0) {
#pragma unroll
            for (int t = 0; t < 4; ++t) {
                int n = n0 + (wid * 4 + t) + 16 * nh;
                float* o = out + ((size_t)bb * LL + n) * 4;
#pragma unroll
                for (int c = 0; c < 4; ++c) atomicAdd(o + c, p[t][c]);
            }
        }
    }
}

extern "C" void kernel_launch(void* const* d_in, const int* in_sizes, int n_in,
                              void* d_out, int out_size, void* d_ws, size_t ws_size,
                              hipStream_t stream) {
    const int*   ex   = (const int*)d_in[0];
    const float* kern = (const float*)d_in[1];
    const float* bias = (const float*)d_in[2];
    const float* dw   = (const float*)d_in[3];
    const float* db   = (const float*)d_in[4];
    float* out = (float*)d_out;

    _Float16* At = (_Float16*)d_ws;                                   // 12.58 MB
    _Float16* XB = (_Float16*)((char*)d_ws + (size_t)FF * LL * 2);    // +3.05 MB

    hipLaunchKernelGGL(prologue, dim3(5386), dim3(256), 0, stream,
                       kern, At, ex, XB, db, out);
    hipLaunchKernelGGL(conv_main, dim3(1536), dim3(256), 0, stream, At, XB, bias, dw, out);
}

// Round 10
// 570.143 us; speedup vs baseline: 4.9432x; 1.1043x over previous
//
#include <hip/hip_runtime.h>

#define FF 512
#define LL 12288
#define NJC 1556   // XB chunk count: max jc touched = 1553 (incl. K-roundup + prefetch)
#define NR 128     // XB rows = 16 shifts x 8 batches

typedef _Float16 half8 __attribute__((ext_vector_type(8)));
typedef float    f32x4 __attribute__((ext_vector_type(4)));

// ---------------- Fused prologue: 3 ranges of blockIdx, disjoint outputs ----
// [0,3072)        build_At : kernel fp32 -> f16, MFMA-A-fragment tiled
//                  At chunk (ft,dc,lane): elem_i = kernel[ft*16+(lane&15)][dc*32+(lane>>4)*8+i]
// [3072,3850)     build_XB : B chunk-major; XB[jc][s*8+b] elem_i = x_b[LL-1-(8jc+i)-s]
//                  (zero when idx<0 -> causal mask, incl. jc>=1536 pad tail)
// [3850,5386)     init_out : out = dense_b broadcast
__global__ __launch_bounds__(256) void prologue(const float* __restrict__ kern,
                                                _Float16* __restrict__ At,
                                                const int* __restrict__ ex,
                                                _Float16* __restrict__ XB,
                                                const float* __restrict__ db,
                                                float* __restrict__ out) {
    int bxx = blockIdx.x;
    if (bxx < 3072) {
        int tid  = bxx * 256 + threadIdx.x;             // 786432 = 512*12288/8
        int lane = tid & 63;
        int rest = tid >> 6;                            // ft*384 + dc
        int dc   = rest % 384;
        int ft   = rest / 384;
        int f    = ft * 16 + (lane & 15);
        int d0   = dc * 32 + (lane >> 4) * 8;
        const float* src = kern + (size_t)f * LL + d0;
        half8 v;
#pragma unroll
        for (int i = 0; i < 8; ++i) v[i] = (_Float16)src[i];
        ((half8*)At)[tid] = v;
    } else if (bxx < 3850) {
        int tid = (bxx - 3072) * 256 + threadIdx.x;     // 199168 = NJC*NR
        if (tid >= NJC * NR) return;
        int r  = tid & 127;
        int jc = tid >> 7;
        int s  = r >> 3, b = r & 7;
        int j0 = jc * 8;
        half8 v;
#pragma unroll
        for (int i = 0; i < 8; ++i) {
            int idx = LL - 1 - (j0 + i) - s;
            float x = 0.f;
            if (idx >= 0) x = (float)ex[b * LL + idx] * 0.5f - 1.0f;
            v[i] = (_Float16)x;
        }
        ((half8*)XB)[tid] = v;
    } else {
        int tid = (bxx - 3850) * 256 + threadIdx.x;     // 393216
        out[tid] = db[tid & 3];
    }
}

__device__ __forceinline__ void gl_lds16(const half8* g, half8* l) {
    __builtin_amdgcn_global_load_lds((const __attribute__((address_space(1))) void*)g,
                                     (__attribute__((address_space(3))) void*)l, 16, 0, 0);
}

// ---------------- Main: r7 inner loop, EQUAL-LENGTH triple blocks ----------
// 512 blocks = 4 f_blk x 128 triples = exactly one full-residency round
// (256 CU x 2 blocks/CU), every block identical duration. Triple g covers
// n-tiles {256+g, 192+g, 127-2g} (g<64) or {256+g, 64+g, 254-2g} (g>=64):
// exact partition of 0..383 with K32-sums 574/575 -> zero ragged tail.
// Inner loop IDENTICAL to r7: block 128f x 256cols, 4 waves, wave tile
// 128x64 (8x4 mfma 16x16x32 f16), BK=128 macro-steps, 32KB A tile
// double-buffered (64KB LDS), entry s_barrier + setprio(1) per 32-MFMA
// cluster, no exit barrier, one __syncthreads per macro. K rounded up to x4;
// tail MFMAs hit XB's causal zero pad (max jc = 1553 < NJC).
__global__ __launch_bounds__(256, 2) void conv_main(const _Float16* __restrict__ At,
                                                    const _Float16* __restrict__ XB,
                                                    const float* __restrict__ bias,
                                                    const float* __restrict__ dw,
                                                    float* __restrict__ out) {
    __shared__ half8 Abuf[2][4][8][64];   // 64 KB: [buf][sub][ft][lane]

    int bx    = blockIdx.x;
    int slot  = bx & 7;                // XCD pin: f_blk per XCD pair for L2 reuse
    int f_blk = slot >> 1;             // [0,4)
    int g     = ((bx >> 3) << 1) | (slot & 1);        // triple index [0,128)

    int n_t[3];
    n_t[0] = 256 + g;
    n_t[1] = (g < 64) ? 192 + g : 64 + g;
    n_t[2] = (g < 64) ? 127 - 2 * g : 254 - 2 * g;

    int tid  = threadIdx.x;
    int lane = tid & 63;
    int wid  = tid >> 6;
    int quad = lane >> 4;
    int bb   = lane & 7;
    int nh   = (lane >> 3) & 1;

    // A staging: wave wid stages ft = wid and wid+4; 1KB contiguous per load.
    const half8* Ag  = (const half8*)At;
    const half8* ag0 = Ag + ((size_t)(f_blk * 8 + wid) * 384) * 64 + lane;
    const half8* ag1 = Ag + ((size_t)(f_blk * 8 + wid + 4) * 384) * 64 + lane;
    const half8* Bg  = (const half8*)XB;

    for (int tile = 0; tile < 3; ++tile) {
        int n_blk = n_t[tile];
        int n0 = n_blk << 5;
        int M  = (n_blk + 4) >> 2;     // ceil((n_blk+1)/4) macro (BK=128) steps

        // B pointers (half8 units): idx = jc*128 + r; per-K32 advance = 512.
        int jc0 = 1534 - 4 * n_blk + quad - 2 * nh;
        const half8* pB[4];
#pragma unroll
        for (int t = 0; t < 4; ++t) {
            int tt = wid * 4 + t;
            int r  = (15 - tt) * 8 + bb;
            pB[t] = Bg + (size_t)jc0 * 128 + r;
        }

        f32x4 acc[8][4];
#pragma unroll
        for (int r8 = 0; r8 < 8; ++r8)
#pragma unroll
            for (int t = 0; t < 4; ++t) acc[r8][t] = (f32x4){0.f, 0.f, 0.f, 0.f};

        // tile prologue: stage macro 0 -> buf0, load B(0)
#pragma unroll
        for (int sub = 0; sub < 4; ++sub) {
            gl_lds16(ag0 + (size_t)sub * 64, &Abuf[0][sub][wid][lane]);
            gl_lds16(ag1 + (size_t)sub * 64, &Abuf[0][sub][wid + 4][lane]);
        }
        half8 bcur[4], bnxt[4];
#pragma unroll
        for (int t = 0; t < 4; ++t) bcur[t] = pB[t][0];
        __syncthreads();

        for (int mc = 0; mc < M; ++mc) {
            int buf = mc & 1;
            if (mc + 1 < M) {
                size_t oa = (size_t)(mc + 1) * 256;       // 4 subs x 64 chunks
#pragma unroll
                for (int sub = 0; sub < 4; ++sub) {
                    gl_lds16(ag0 + oa + (size_t)sub * 64, &Abuf[buf ^ 1][sub][wid][lane]);
                    gl_lds16(ag1 + oa + (size_t)sub * 64, &Abuf[buf ^ 1][sub][wid + 4][lane]);
                }
            }
#pragma unroll
            for (int sub = 0; sub < 4; ++sub) {
                int dc = mc * 4 + sub;
                size_t ob = (size_t)(dc + 1) * 512;
#pragma unroll
                for (int t = 0; t < 4; ++t) bnxt[t] = pB[t][ob];
                half8 a[8];
#pragma unroll
                for (int r8 = 0; r8 < 8; ++r8) a[r8] = Abuf[buf][sub][r8][lane];
                __builtin_amdgcn_s_barrier();      // cluster entry: waves aligned
                __builtin_amdgcn_s_setprio(1);
#pragma unroll
                for (int r8 = 0; r8 < 8; ++r8)
#pragma unroll
                    for (int t = 0; t < 4; ++t)
                        acc[r8][t] = __builtin_amdgcn_mfma_f32_16x16x32_f16(a[r8], bcur[t], acc[r8][t], 0, 0, 0);
                __builtin_amdgcn_s_setprio(0);
#pragma unroll
                for (int t = 0; t < 4; ++t) bcur[t] = bnxt[t];
            }
            __syncthreads();
        }

        // tile epilogue: bias + relu + dense over this block's 128 f rows.
        // C/D layout: col = lane&15, row = quad*4 + reg.
        float p[4][4] = {{0.f}};
#pragma unroll
        for (int r8 = 0; r8 < 8; ++r8) {
#pragma unroll
            for (int reg = 0; reg < 4; ++reg) {
                int f = f_blk * 128 + r8 * 16 + quad * 4 + reg;
                float bs = bias[f];
                float4 w = *(const float4*)(dw + (size_t)f * 4);
#pragma unroll
                for (int t = 0; t < 4; ++t) {
                    float y = fmaxf(acc[r8][t][reg] + bs, 0.f);
                    p[t][0] += y * w.x; p[t][1] += y * w.y;
                    p[t][2] += y * w.z; p[t][3] += y * w.w;
                }
            }
        }
#pragma unroll
        for (int t = 0; t < 4; ++t)
#pragma unroll
            for (int c = 0; c < 4; ++c) {
                float v = p[t][c];
                v += __shfl_xor(v, 16, 64);
                v += __shfl_xor(v, 32, 64);
                p[t][c] = v;
            }
        if (quad == 0) {
#pragma unroll
            for (int t = 0; t < 4; ++t) {
                int n = n0 + (wid * 4 + t) + 16 * nh;
                float* o = out + ((size_t)bb * LL + n) * 4;
#pragma unroll
                for (int c = 0; c < 4; ++c) atomicAdd(o + c, p[t][c]);
            }
        }
    }
}

extern "C" void kernel_launch(void* const* d_in, const int* in_sizes, int n_in,
                              void* d_out, int out_size, void* d_ws, size_t ws_size,
                              hipStream_t stream) {
    const int*   ex   = (const int*)d_in[0];
    const float* kern = (const float*)d_in[1];
    const float* bias = (const float*)d_in[2];
    const float* dw   = (const float*)d_in[3];
    const float* db   = (const float*)d_in[4];
    float* out = (float*)d_out;

    _Float16* At = (_Float16*)d_ws;                                   // 12.58 MB
    _Float16* XB = (_Float16*)((char*)d_ws + (size_t)FF * LL * 2);    // +3.05 MB

    hipLaunchKernelGGL(prologue, dim3(5386), dim3(256), 0, stream,
                       kern, At, ex, XB, db, out);
    hipLaunchKernelGGL(conv_main, dim3(512), dim3(256), 0, stream, At, XB, bias, dw, out);
}

// Round 11
// 498.713 us; speedup vs baseline: 5.6512x; 1.1432x over previous
//
#include <hip/hip_runtime.h>

#define FF 512
#define LL 12288
#define NJC 1556   // XB chunk count: max jc touched = 1553 (incl. K-roundup + prefetch)
#define NR 128     // XB rows = 16 shifts x 8 batches

typedef _Float16 half8 __attribute__((ext_vector_type(8)));
typedef float    f32x4 __attribute__((ext_vector_type(4)));

// ---------------- Fused prologue: 3 ranges of blockIdx, disjoint outputs ----
// [0,3072)        build_At : kernel fp32 -> f16, MFMA-A-fragment tiled
//                  At chunk (ft,dc,lane): elem_i = kernel[ft*16+(lane&15)][dc*32+(lane>>4)*8+i]
// [3072,3850)     build_XB : B chunk-major; XB[jc][s*8+b] elem_i = x_b[LL-1-(8jc+i)-s]
//                  (zero when idx<0 -> causal mask, incl. jc>=1536 pad tail)
// [3850,5386)     init_out : out = dense_b broadcast
__global__ __launch_bounds__(256) void prologue(const float* __restrict__ kern,
                                                _Float16* __restrict__ At,
                                                const int* __restrict__ ex,
                                                _Float16* __restrict__ XB,
                                                const float* __restrict__ db,
                                                float* __restrict__ out) {
    int bxx = blockIdx.x;
    if (bxx < 3072) {
        int tid  = bxx * 256 + threadIdx.x;             // 786432 = 512*12288/8
        int lane = tid & 63;
        int rest = tid >> 6;                            // ft*384 + dc
        int dc   = rest % 384;
        int ft   = rest / 384;
        int f    = ft * 16 + (lane & 15);
        int d0   = dc * 32 + (lane >> 4) * 8;
        const float* src = kern + (size_t)f * LL + d0;
        half8 v;
#pragma unroll
        for (int i = 0; i < 8; ++i) v[i] = (_Float16)src[i];
        ((half8*)At)[tid] = v;
    } else if (bxx < 3850) {
        int tid = (bxx - 3072) * 256 + threadIdx.x;     // 199168 = NJC*NR
        if (tid >= NJC * NR) return;
        int r  = tid & 127;
        int jc = tid >> 7;
        int s  = r >> 3, b = r & 7;
        int j0 = jc * 8;
        half8 v;
#pragma unroll
        for (int i = 0; i < 8; ++i) {
            int idx = LL - 1 - (j0 + i) - s;
            float x = 0.f;
            if (idx >= 0) x = (float)ex[b * LL + idx] * 0.5f - 1.0f;
            v[i] = (_Float16)x;
        }
        ((half8*)XB)[tid] = v;
    } else {
        int tid = (bxx - 3850) * 256 + threadIdx.x;     // 393216
        out[tid] = db[tid & 3];
    }
}

__device__ __forceinline__ void gl_lds16(const half8* g, half8* l) {
    __builtin_amdgcn_global_load_lds((const __attribute__((address_space(1))) void*)g,
                                     (__attribute__((address_space(3))) void*)l, 16, 0, 0);
}

// ---------------- Main: A via LDS (BK=128 macro-steps), B register-direct --
// Block 128f x 256cols, 4 waves, wave tile 128x64 (8x4 mfma 16x16x32 f16).
// One __syncthreads per 4 K32 sub-steps; 32KB A tile double-buffered (64KB).
// PHASE-INTERLOCK (T5, entry-only): each sub-step's 32-MFMA cluster starts at
// an s_barrier and runs at setprio(1). Entry barrier keeps the block's 4 waves
// phase-locked (creating a {MFMA-phase vs load-phase} split between the two
// co-resident blocks per SIMD); no exit barrier — fast waves overlap their
// next-sub-step loads with siblings' MFMA tails. No sched_barrier walls, no
// manual waitcnt. K rounded up to x4; tail MFMAs hit XB's causal zero pad.
// NOTE (r8-r10 falsifications): 3 waves/SIMD spills (232-reg working set needs
// the 256 tier; 170-tier impossible at this tile); smaller tiles lose more
// arithmetic intensity than occupancy coverage gains (r9); equal-length
// multi-tile packing destroys the descending-K L2 locality (r10).
__global__ __launch_bounds__(256, 2) void conv_main(const _Float16* __restrict__ At,
                                                    const _Float16* __restrict__ XB,
                                                    const float* __restrict__ bias,
                                                    const float* __restrict__ dw,
                                                    float* __restrict__ out) {
    __shared__ half8 Abuf[2][4][8][64];   // 64 KB: [buf][sub][ft][lane]

    int bx    = blockIdx.x;
    int slot  = bx & 7;                // XCD pin: f_blk per XCD pair for L2 reuse
    int f_blk = slot >> 1;             // [0,4)
    int n_blk = 383 - ((bx >> 3) * 2 + (slot & 1));   // largest K first
    int n0 = n_blk << 5;
    int M  = (n_blk + 4) >> 2;         // ceil((n_blk+1)/4) macro (BK=128) steps

    int tid  = threadIdx.x;
    int lane = tid & 63;
    int wid  = tid >> 6;
    int quad = lane >> 4;
    int bb   = lane & 7;
    int nh   = (lane >> 3) & 1;

    // A staging: wave wid stages ft = wid and wid+4; 1KB contiguous per load.
    const half8* Ag  = (const half8*)At;
    const half8* ag0 = Ag + ((size_t)(f_blk * 8 + wid) * 384) * 64 + lane;
    const half8* ag1 = Ag + ((size_t)(f_blk * 8 + wid + 4) * 384) * 64 + lane;

    // B pointers (half8 units): idx = jc*128 + r; per-K32 advance = 4*128 = 512.
    const half8* Bg = (const half8*)XB;
    int jc0 = 1534 - 4 * n_blk + quad - 2 * nh;
    const half8* pB[4];
#pragma unroll
    for (int t = 0; t < 4; ++t) {
        int tt = wid * 4 + t;
        int r  = (15 - tt) * 8 + bb;
        pB[t] = Bg + (size_t)jc0 * 128 + r;
    }

    f32x4 acc[8][4];
#pragma unroll
    for (int r8 = 0; r8 < 8; ++r8)
#pragma unroll
        for (int t = 0; t < 4; ++t) acc[r8][t] = (f32x4){0.f, 0.f, 0.f, 0.f};

    // prologue: stage macro 0 -> buf0, load B(0)
#pragma unroll
    for (int sub = 0; sub < 4; ++sub) {
        gl_lds16(ag0 + (size_t)sub * 64, &Abuf[0][sub][wid][lane]);
        gl_lds16(ag1 + (size_t)sub * 64, &Abuf[0][sub][wid + 4][lane]);
    }
    half8 bcur[4], bnxt[4];
#pragma unroll
    for (int t = 0; t < 4; ++t) bcur[t] = pB[t][0];
    __syncthreads();

    for (int mc = 0; mc < M; ++mc) {
        int buf = mc & 1;
        if (mc + 1 < M) {
            size_t oa = (size_t)(mc + 1) * 256;           // 4 subs x 64 chunks
#pragma unroll
            for (int sub = 0; sub < 4; ++sub) {
                gl_lds16(ag0 + oa + (size_t)sub * 64, &Abuf[buf ^ 1][sub][wid][lane]);
                gl_lds16(ag1 + oa + (size_t)sub * 64, &Abuf[buf ^ 1][sub][wid + 4][lane]);
            }
        }
#pragma unroll
        for (int sub = 0; sub < 4; ++sub) {
            int dc = mc * 4 + sub;
            size_t ob = (size_t)(dc + 1) * 512;
#pragma unroll
            for (int t = 0; t < 4; ++t) bnxt[t] = pB[t][ob];
            half8 a[8];
#pragma unroll
            for (int r8 = 0; r8 < 8; ++r8) a[r8] = Abuf[buf][sub][r8][lane];
            __builtin_amdgcn_s_barrier();          // cluster entry: waves aligned
            __builtin_amdgcn_s_setprio(1);
#pragma unroll
            for (int r8 = 0; r8 < 8; ++r8)
#pragma unroll
                for (int t = 0; t < 4; ++t)
                    acc[r8][t] = __builtin_amdgcn_mfma_f32_16x16x32_f16(a[r8], bcur[t], acc[r8][t], 0, 0, 0);
            __builtin_amdgcn_s_setprio(0);
#pragma unroll
            for (int t = 0; t < 4; ++t) bcur[t] = bnxt[t];
        }
        __syncthreads();
    }

    // Epilogue: bias + relu + dense over this block's 128 f rows.
    // C/D layout: col = lane&15, row = quad*4 + reg.
    float p[4][4] = {{0.f}};
#pragma unroll
    for (int r8 = 0; r8 < 8; ++r8) {
#pragma unroll
        for (int reg = 0; reg < 4; ++reg) {
            int f = f_blk * 128 + r8 * 16 + quad * 4 + reg;
            float bs = bias[f];
            float4 w = *(const float4*)(dw + (size_t)f * 4);
#pragma unroll
            for (int t = 0; t < 4; ++t) {
                float y = fmaxf(acc[r8][t][reg] + bs, 0.f);
                p[t][0] += y * w.x; p[t][1] += y * w.y;
                p[t][2] += y * w.z; p[t][3] += y * w.w;
            }
        }
    }
#pragma unroll
    for (int t = 0; t < 4; ++t)
#pragma unroll
        for (int c = 0; c < 4; ++c) {
            float v = p[t][c];
            v += __shfl_xor(v, 16, 64);
            v += __shfl_xor(v, 32, 64);
            p[t][c] = v;
        }
    if (quad == 0) {
#pragma unroll
        for (int t = 0; t < 4; ++t) {
            int n = n0 + (wid * 4 + t) + 16 * nh;
            float* o = out + ((size_t)bb * LL + n) * 4;
#pragma unroll
            for (int c = 0; c < 4; ++c) atomicAdd(o + c, p[t][c]);
        }
    }
}

extern "C" void kernel_launch(void* const* d_in, const int* in_sizes, int n_in,
                              void* d_out, int out_size, void* d_ws, size_t ws_size,
                              hipStream_t stream) {
    const int*   ex   = (const int*)d_in[0];
    const float* kern = (const float*)d_in[1];
    const float* bias = (const float*)d_in[2];
    const float* dw   = (const float*)d_in[3];
    const float* db   = (const float*)d_in[4];
    float* out = (float*)d_out;

    _Float16* At = (_Float16*)d_ws;                                   // 12.58 MB
    _Float16* XB = (_Float16*)((char*)d_ws + (size_t)FF * LL * 2);    // +3.05 MB

    hipLaunchKernelGGL(prologue, dim3(5386), dim3(256), 0, stream,
                       kern, At, ex, XB, db, out);
    hipLaunchKernelGGL(conv_main, dim3(1536), dim3(256), 0, stream, At, XB, bias, dw, out);
}